// Round 2
// baseline (189.309 us; speedup 1.0000x reference)
//
#include <hip/hip_runtime.h>
#include <hip/hip_bf16.h>

// ---------- common ----------
typedef __attribute__((ext_vector_type(8))) short short8;
typedef __attribute__((ext_vector_type(4))) float f32x4;
typedef __attribute__((ext_vector_type(4))) unsigned short ushort4v;

#define DI __device__ __forceinline__

DI unsigned short f2bf(float f) {
  union { float f; unsigned int u; } a; a.f = f;
  unsigned int u = a.u;
  return (unsigned short)((u + 0x7FFFu + ((u >> 16) & 1u)) >> 16);
}

// Problem constants
// B=8, H1=W1=56, N1=3136, C1=512, C2=256, NH=8, HD=64, WS=7, windows 8x8=64
// pooled Hp=Wp=56, Np=3136, M = B*3136 = 25088

// ---------- f32 -> bf16 convert ----------
__global__ __launch_bounds__(256)
void cvt_bf16(const float* __restrict__ in, unsigned short* __restrict__ out, int n) {
  int i = (blockIdx.x * 256 + threadIdx.x) * 4;
  if (i >= n) return;
  float4 v = *(const float4*)&in[i];
  ushort4v o = { f2bf(v.x), f2bf(v.y), f2bf(v.z), f2bf(v.w) };
  *(ushort4v*)&out[i] = o;
}

// ---------- 2x2 avgpool + convert: y (B,112*112,256) f32 -> yp (B*3136,256) bf16 ----------
__global__ __launch_bounds__(256)
void pool_cvt(const float* __restrict__ y, unsigned short* __restrict__ out) {
  int t = blockIdx.x * 256 + threadIdx.x;      // 25088 * 64 threads
  int cv = (t & 63) * 4;
  int bp = t >> 6;
  int b = bp / 3136, p = bp % 3136;
  int hp = p / 56, wp = p % 56;
  const float* src = y + (((size_t)b * 12544) + hp * 224 + wp * 2) * 256 + cv;
  float4 a0 = *(const float4*)(src);
  float4 a1 = *(const float4*)(src + 256);
  float4 a2 = *(const float4*)(src + 28672);
  float4 a3 = *(const float4*)(src + 28672 + 256);
  float4 av;
  av.x = (a0.x + a1.x + a2.x + a3.x) * 0.25f;
  av.y = (a0.y + a1.y + a2.y + a3.y) * 0.25f;
  av.z = (a0.z + a1.z + a2.z + a3.z) * 0.25f;
  av.w = (a0.w + a1.w + a2.w + a3.w) * 0.25f;
  ushort4v o = { f2bf(av.x), f2bf(av.y), f2bf(av.z), f2bf(av.w) };
  *(ushort4v*)&out[(size_t)bp * 256 + cv] = o;
}

// ---------- LayerNorm(256) + exact GELU, f32 in -> bf16 out ----------
__global__ __launch_bounds__(256)
void ln_gelu_k(const float* __restrict__ z, const float* __restrict__ gn,
               const float* __restrict__ bn, unsigned short* __restrict__ out) {
  int row = blockIdx.x * 4 + (threadIdx.x >> 6);
  int lane = threadIdx.x & 63;
  const float* zr = z + (size_t)row * 256 + lane * 4;
  float4 v = *(const float4*)zr;
  float s = v.x + v.y + v.z + v.w;
  float sq = v.x * v.x + v.y * v.y + v.z * v.z + v.w * v.w;
#pragma unroll
  for (int m = 1; m <= 32; m <<= 1) { s += __shfl_xor(s, m); sq += __shfl_xor(sq, m); }
  float mean = s * (1.f / 256.f);
  float var = sq * (1.f / 256.f) - mean * mean;
  float rstd = rsqrtf(var + 1e-5f);
  float4 g = *(const float4*)&gn[lane * 4];
  float4 bb = *(const float4*)&bn[lane * 4];
  float t[4];
  t[0] = (v.x - mean) * rstd * g.x + bb.x;
  t[1] = (v.y - mean) * rstd * g.y + bb.y;
  t[2] = (v.z - mean) * rstd * g.z + bb.z;
  t[3] = (v.w - mean) * rstd * g.w + bb.w;
#pragma unroll
  for (int i = 0; i < 4; ++i)
    t[i] = 0.5f * t[i] * (1.f + erff(t[i] * 0.70710678118654752f));
  ushort4v o = { f2bf(t[0]), f2bf(t[1]), f2bf(t[2]), f2bf(t[3]) };
  *(ushort4v*)&out[(size_t)row * 256 + lane * 4] = o;
}

// ---------- 128x128 bf16 MFMA GEMM: out[m,n] = sum_k A[m,k]*Bw[n,k] ----------
// EPI 0: q windows (bf16)   EPI 1: f32 + bias (N=256, SR conv)
// EPI 2: kv windows (bf16, outp=k_win, out2=v_win)   EPI 3: f32 + bias (final out)
template<int K, int N, int EPI>
__global__ __launch_bounds__(256, 2)
void gemm128(const unsigned short* __restrict__ A,
             const unsigned short* __restrict__ Bw,
             void* __restrict__ outp,
             const float* __restrict__ bias,
             unsigned short* __restrict__ out2) {
  __shared__ unsigned short sA[128 * 64];
  __shared__ unsigned short sB[128 * 64];
  const int tid = threadIdx.x;
  const int wv = tid >> 6;
  const int lane = tid & 63;
  const int m0 = blockIdx.y * 128;
  const int n0 = blockIdx.x * 128;
  const int wm = (wv >> 1) * 64;
  const int wn = (wv & 1) * 64;
  const int lr = lane & 15;
  const int lk8 = (lane >> 4) * 8;
  const int lr4 = (lane >> 4) * 4;

  f32x4 acc[4][4];
#pragma unroll
  for (int i = 0; i < 4; ++i)
#pragma unroll
    for (int j = 0; j < 4; ++j) acc[i][j] = (f32x4){0.f, 0.f, 0.f, 0.f};

  const int srow = wv * 32 + (lane >> 3);
  const int scol = (lane & 7) * 8;
  const unsigned short* gA = A + (size_t)(m0 + srow) * K + scol;
  const unsigned short* gB = Bw + (size_t)(n0 + srow) * K + scol;

  for (int kt = 0; kt < K; kt += 64) {
#pragma unroll
    for (int c = 0; c < 4; ++c) {
      __builtin_amdgcn_global_load_lds(
          (const __attribute__((address_space(1))) void*)(gA + (size_t)(c * 8) * K + kt),
          (__attribute__((address_space(3))) void*)&sA[(wv * 32 + c * 8) * 64], 16, 0, 0);
      __builtin_amdgcn_global_load_lds(
          (const __attribute__((address_space(1))) void*)(gB + (size_t)(c * 8) * K + kt),
          (__attribute__((address_space(3))) void*)&sB[(wv * 32 + c * 8) * 64], 16, 0, 0);
    }
    __syncthreads();
#pragma unroll
    for (int ks = 0; ks < 2; ++ks) {
      short8 af[4], bfr[4];
#pragma unroll
      for (int i = 0; i < 4; ++i)
        af[i] = *(const short8*)&sA[(wm + i * 16 + lr) * 64 + ks * 32 + lk8];
#pragma unroll
      for (int j = 0; j < 4; ++j)
        bfr[j] = *(const short8*)&sB[(wn + j * 16 + lr) * 64 + ks * 32 + lk8];
#pragma unroll
      for (int i = 0; i < 4; ++i)
#pragma unroll
        for (int j = 0; j < 4; ++j)
          acc[i][j] = __builtin_amdgcn_mfma_f32_16x16x32_bf16(af[i], bfr[j], acc[i][j], 0, 0, 0);
    }
    __syncthreads();
  }

#pragma unroll
  for (int i = 0; i < 4; ++i) {
#pragma unroll
    for (int j = 0; j < 4; ++j) {
#pragma unroll
      for (int r = 0; r < 4; ++r) {
        const int gm = m0 + wm + i * 16 + lr4 + r;
        const int gc = n0 + wn + j * 16 + lr;
        const float v = acc[i][j][r];
        if constexpr (EPI == 1 || EPI == 3) {
          ((float*)outp)[(size_t)gm * N + gc] = v + bias[gc];
        } else if constexpr (EPI == 0) {
          const int b = gm / 3136, pos = gm % 3136;
          const int h = pos / 56, ww = pos % 56;
          const int head = gc >> 6, d = gc & 63;
          const size_t idx = ((((size_t)(b * 8 + head)) * 64 + (h / 7) * 8 + (ww / 7)) * 49
                              + (h % 7) * 7 + (ww % 7)) * 64 + d;
          ((unsigned short*)outp)[idx] = f2bf(v);
        } else { // EPI == 2: kv scatter
          const int b = gm / 3136, pos = gm % 3136;
          const int h = pos / 56, ww = pos % 56;
          const int sel = gc >> 9, cc = gc & 511;
          const int head = cc >> 6, d = cc & 63;
          unsigned short* dst = sel ? out2 : (unsigned short*)outp;
          const size_t idx = ((((size_t)(b * 8 + head)) * 64 + (h / 7) * 8 + (ww / 7)) * 49
                              + (h % 7) * 7 + (ww % 7)) * 64 + d;
          dst[idx] = f2bf(v);
        }
      }
    }
  }
}

// ---------- windowed attention: one block per (b, head, window) ----------
__global__ __launch_bounds__(256)
void attn_win(const unsigned short* __restrict__ qw,
              const unsigned short* __restrict__ kw,
              const unsigned short* __restrict__ vw,
              unsigned short* __restrict__ aout) {
  __shared__ unsigned short q_s[64 * 64];
  __shared__ unsigned short k_s[64 * 64];
  __shared__ unsigned short vT_s[64 * 72];
  __shared__ unsigned short p_s[64 * 72];

  const int tid = threadIdx.x;
  const int bx = blockIdx.x;
  const int wv = tid >> 6;
  const int lane = tid & 63;
  const int lr = lane & 15;
  const int lk8 = (lane >> 4) * 8;
  const int lr4 = (lane >> 4) * 4;

  const size_t base = (size_t)bx * 3136;
  // q, k tiles (rows >= 49 zeroed)
  for (int i = tid * 8; i < 4096; i += 2048) {
    uint4 zv = make_uint4(0u, 0u, 0u, 0u);
    uint4 qv = zv, kvv = zv;
    if (i < 3136) {
      qv  = *(const uint4*)&qw[base + i];
      kvv = *(const uint4*)&kw[base + i];
    }
    *(uint4*)&q_s[i] = qv;
    *(uint4*)&k_s[i] = kvv;
  }
  // v transposed
  for (int i = tid * 8; i < 4096; i += 2048) {
    int j = i >> 6, d0 = i & 63;
    union { uint4 v; unsigned short u[8]; } t;
    t.v = make_uint4(0u, 0u, 0u, 0u);
    if (i < 3136) t.v = *(const uint4*)&vw[base + i];
#pragma unroll
    for (int e = 0; e < 8; ++e) vT_s[(d0 + e) * 72 + j] = t.u[e];
  }
  __syncthreads();

  // S strip (16 rows per wave x 64 cols)
  f32x4 s[4];
#pragma unroll
  for (int j = 0; j < 4; ++j) s[j] = (f32x4){0.f, 0.f, 0.f, 0.f};
#pragma unroll
  for (int ks = 0; ks < 2; ++ks) {
    short8 aq = *(const short8*)&q_s[(wv * 16 + lr) * 64 + ks * 32 + lk8];
#pragma unroll
    for (int j = 0; j < 4; ++j) {
      short8 bk = *(const short8*)&k_s[(j * 16 + lr) * 64 + ks * 32 + lk8];
      s[j] = __builtin_amdgcn_mfma_f32_16x16x32_bf16(aq, bk, s[j], 0, 0, 0);
    }
  }
  // mask cols >= 49
#pragma unroll
  for (int j = 0; j < 4; ++j) {
    if (j * 16 + lr >= 49) {
#pragma unroll
      for (int r = 0; r < 4; ++r) s[j][r] = -1e30f;
    }
  }
  // softmax over 64 cols (16-lane groups hold cols of the same 4 rows)
  float mx[4], sm[4];
#pragma unroll
  for (int r = 0; r < 4; ++r)
    mx[r] = fmaxf(fmaxf(s[0][r], s[1][r]), fmaxf(s[2][r], s[3][r]));
#pragma unroll
  for (int m = 1; m <= 8; m <<= 1)
#pragma unroll
    for (int r = 0; r < 4; ++r) mx[r] = fmaxf(mx[r], __shfl_xor(mx[r], m));
  const float cexp = 0.125f * 1.4426950408889634f; // scale * log2(e)
  float pv[4][4];
#pragma unroll
  for (int j = 0; j < 4; ++j)
#pragma unroll
    for (int r = 0; r < 4; ++r)
      pv[j][r] = exp2f((s[j][r] - mx[r]) * cexp);
#pragma unroll
  for (int r = 0; r < 4; ++r)
    sm[r] = pv[0][r] + pv[1][r] + pv[2][r] + pv[3][r];
#pragma unroll
  for (int m = 1; m <= 8; m <<= 1)
#pragma unroll
    for (int r = 0; r < 4; ++r) sm[r] += __shfl_xor(sm[r], m);
#pragma unroll
  for (int r = 0; r < 4; ++r) sm[r] = 1.f / sm[r];
#pragma unroll
  for (int j = 0; j < 4; ++j)
#pragma unroll
    for (int r = 0; r < 4; ++r)
      p_s[(wv * 16 + lr4 + r) * 72 + j * 16 + lr] = f2bf(pv[j][r] * sm[r]);
  __syncthreads();

  // O = P V
  f32x4 o[4];
#pragma unroll
  for (int dt = 0; dt < 4; ++dt) o[dt] = (f32x4){0.f, 0.f, 0.f, 0.f};
#pragma unroll
  for (int ks = 0; ks < 2; ++ks) {
    short8 pa = *(const short8*)&p_s[(wv * 16 + lr) * 72 + ks * 32 + lk8];
#pragma unroll
    for (int dt = 0; dt < 4; ++dt) {
      short8 vb = *(const short8*)&vT_s[(dt * 16 + lr) * 72 + ks * 32 + lk8];
      o[dt] = __builtin_amdgcn_mfma_f32_16x16x32_bf16(pa, vb, o[dt], 0, 0, 0);
    }
  }
  // scatter to natural layout (B*3136, 512) bf16
  const int b = bx >> 9;
  const int head = (bx >> 6) & 7;
  const int win = bx & 63;
  const int ht = win >> 3, wt = win & 7;
#pragma unroll
  for (int r = 0; r < 4; ++r) {
    int prow = wv * 16 + lr4 + r;
    if (prow < 49) {
      int wr = prow / 7, wc = prow % 7;
      size_t gm = (size_t)b * 3136 + (ht * 7 + wr) * 56 + wt * 7 + wc;
#pragma unroll
      for (int dt = 0; dt < 4; ++dt)
        aout[gm * 512 + head * 64 + dt * 16 + lr] = f2bf(o[dt][r]);
    }
  }
}

// ---------- launcher ----------
extern "C" void kernel_launch(void* const* d_in, const int* in_sizes, int n_in,
                              void* d_out, int out_size, void* d_ws, size_t ws_size,
                              hipStream_t stream) {
  const float* x     = (const float*)d_in[0];
  const float* y     = (const float*)d_in[1];
  const float* Wq    = (const float*)d_in[2];
  const float* Wkv   = (const float*)d_in[3];
  const float* Wproj = (const float*)d_in[4];
  const float* bproj = (const float*)d_in[5];
  const float* Wsr   = (const float*)d_in[6];
  const float* bsr   = (const float*)d_in[7];
  const float* gn    = (const float*)d_in[8];
  const float* bn    = (const float*)d_in[9];
  float* out = (float*)d_out;

  // Workspace layout (all sizes in BYTES; element counts * 2 for bf16).
  // regA: 25088*512 bf16 (xb) -> 25088*256 f32 (z) -> 25088*512 bf16 (attn_out)
  // q/k/v windows: 8*8*64 windows * 49 rows(padded from 3136 elems) * 64 d = 12,845,056 elems = 25,690,112 B each
  char* ws = (char*)d_ws;
  unsigned short* Wq_b    = (unsigned short*)ws; ws += 524288;
  unsigned short* Wkv_b   = (unsigned short*)ws; ws += 524288;
  unsigned short* Wproj_b = (unsigned short*)ws; ws += 524288;
  unsigned short* Wsr_b   = (unsigned short*)ws; ws += 131072;
  unsigned short* regA    = (unsigned short*)ws; ws += 25690112;
  unsigned short* q_win   = (unsigned short*)ws; ws += 25690112;
  unsigned short* regC    = (unsigned short*)ws; ws += 12845056; // yp_b -> y2b (25088*256 bf16)
  unsigned short* k_win   = (unsigned short*)ws; ws += 25690112; // FIXED: was 12,845,056 B (elements-vs-bytes bug)
  unsigned short* v_win   = (unsigned short*)ws; ws += 25690112; // FIXED: same

  // weight + input converts
  cvt_bf16<<<256, 256, 0, stream>>>(Wq, Wq_b, 262144);
  cvt_bf16<<<256, 256, 0, stream>>>(Wkv, Wkv_b, 262144);
  cvt_bf16<<<256, 256, 0, stream>>>(Wproj, Wproj_b, 262144);
  cvt_bf16<<<64, 256, 0, stream>>>(Wsr, Wsr_b, 65536);
  cvt_bf16<<<12544, 256, 0, stream>>>(x, regA, 12845056);

  // q projection -> window layout
  gemm128<512, 512, 0><<<dim3(4, 196), 256, 0, stream>>>(regA, Wq_b, q_win, nullptr, nullptr);

  // KV preprocess
  pool_cvt<<<6272, 256, 0, stream>>>(y, regC);
  gemm128<256, 256, 1><<<dim3(2, 196), 256, 0, stream>>>(regC, Wsr_b, (void*)regA, bsr, nullptr);
  ln_gelu_k<<<6272, 256, 0, stream>>>((const float*)regA, gn, bn, regC);

  // kv projection -> window layouts
  gemm128<256, 1024, 2><<<dim3(8, 196), 256, 0, stream>>>(regC, Wkv_b, k_win, nullptr, v_win);

  // windowed attention -> natural layout bf16 (reuses regA)
  attn_win<<<4096, 256, 0, stream>>>(q_win, k_win, v_win, regA);

  // output projection + bias -> f32 d_out
  gemm128<512, 512, 3><<<dim3(4, 196), 256, 0, stream>>>(regA, Wproj_b, out, bproj, nullptr);
}

// Round 3
// 177.525 us; speedup vs baseline: 1.0664x; 1.0664x over previous
//
#include <hip/hip_runtime.h>
#include <hip/hip_bf16.h>

// ---------- common ----------
typedef __attribute__((ext_vector_type(8))) short short8;
typedef __attribute__((ext_vector_type(4))) float f32x4;
typedef __attribute__((ext_vector_type(4))) unsigned short ushort4v;

#define DI __device__ __forceinline__

DI unsigned short f2bf(float f) {
  union { float f; unsigned int u; } a; a.f = f;
  unsigned int u = a.u;
  return (unsigned short)((u + 0x7FFFu + ((u >> 16) & 1u)) >> 16);
}

// Problem constants
// B=8, H1=W1=56, N1=3136, C1=512, C2=256, NH=8, HD=64, WS=7, windows 8x8=64
// pooled Hp=Wp=56, Np=3136, M = B*3136 = 25088

// ---------- all f32 -> bf16 converts in one launch ----------
// segments: x (12,845,056) | Wq (262,144) | Wkv (262,144) | Wproj (262,144) | Wsr (65,536)
__global__ __launch_bounds__(256)
void cvt_all(const float* __restrict__ x, const float* __restrict__ Wq,
             const float* __restrict__ Wkv, const float* __restrict__ Wproj,
             const float* __restrict__ Wsr,
             unsigned short* __restrict__ xb, unsigned short* __restrict__ Wq_b,
             unsigned short* __restrict__ Wkv_b, unsigned short* __restrict__ Wproj_b,
             unsigned short* __restrict__ Wsr_b) {
  long i = (long)(blockIdx.x * 256 + threadIdx.x) * 4;
  const float* src; unsigned short* dst; long off;
  if (i < 12845056L)      { src = x;     dst = xb;      off = i; }
  else if (i < 13107200L) { src = Wq;    dst = Wq_b;    off = i - 12845056L; }
  else if (i < 13369344L) { src = Wkv;   dst = Wkv_b;   off = i - 13107200L; }
  else if (i < 13631488L) { src = Wproj; dst = Wproj_b; off = i - 13369344L; }
  else                    { src = Wsr;   dst = Wsr_b;   off = i - 13631488L; }
  float4 v = *(const float4*)&src[off];
  ushort4v o = { f2bf(v.x), f2bf(v.y), f2bf(v.z), f2bf(v.w) };
  *(ushort4v*)&dst[off] = o;
}

// ---------- fused: 2x2 avgpool -> 1x1 conv (GEMM) -> +bias -> LayerNorm -> GELU -> bf16 ----------
// One block = 64 rows (pooled pixels) x full N=256. K=256. 4 waves, each 64x64 output quadrant.
__global__ __launch_bounds__(256)
void sr_ln_gelu(const float* __restrict__ y, const unsigned short* __restrict__ Wsr_b,
                const float* __restrict__ bsr, const float* __restrict__ gn,
                const float* __restrict__ bn, unsigned short* __restrict__ out) {
  __shared__ unsigned short sA[64 * 64];
  __shared__ unsigned short sB[256 * 64];
  __shared__ float red[64 * 8];  // [row][wave*2 + {sum,sq}]

  const int tid = threadIdx.x;
  const int wv = tid >> 6;
  const int lane = tid & 63;
  const int lr = lane & 15;
  const int lk8 = (lane >> 4) * 8;
  const int lr4 = (lane >> 4) * 4;
  const int m0 = blockIdx.x * 64;

  f32x4 acc[4][4];
#pragma unroll
  for (int i = 0; i < 4; ++i)
#pragma unroll
    for (int j = 0; j < 4; ++j) acc[i][j] = (f32x4){0.f, 0.f, 0.f, 0.f};

  // A staging geometry: wave wv owns rows wv*16 .. wv*16+15 (two 8-row chunks)
  const int row0 = wv * 16 + (lane >> 3);
  const int row1 = row0 + 8;
  const int cch = (lane & 7) * 8;  // channel offset within K-step
  size_t sbase[2];
#pragma unroll
  for (int cc = 0; cc < 2; ++cc) {
    int gm = m0 + (cc ? row1 : row0);
    int b = gm / 3136, p = gm % 3136;
    int hp = p / 56, wp = p % 56;
    sbase[cc] = (((size_t)b * 12544) + hp * 224 + wp * 2) * 256 + cch;
  }
  const int arow[2] = { row0, row1 };

  for (int kt = 0; kt < 256; kt += 64) {
    // B: 256 rows x 64 cols via global_load_lds; wave wv stages rows wv*64..+64
#pragma unroll
    for (int c = 0; c < 8; ++c) {
      __builtin_amdgcn_global_load_lds(
          (const __attribute__((address_space(1))) void*)
              (Wsr_b + (size_t)(wv * 64 + c * 8 + (lane >> 3)) * 256 + cch + kt),
          (__attribute__((address_space(3))) void*)&sB[(wv * 64 + c * 8) * 64], 16, 0, 0);
    }
    // A: fused 2x2 avgpool, f32 -> bf16, reg-staged
#pragma unroll
    for (int cc = 0; cc < 2; ++cc) {
      const float* s = y + sbase[cc] + kt;
      float4 a0 = *(const float4*)(s);
      float4 a1 = *(const float4*)(s + 4);
      float4 b0 = *(const float4*)(s + 256);
      float4 b1 = *(const float4*)(s + 260);
      float4 c0 = *(const float4*)(s + 28672);
      float4 c1 = *(const float4*)(s + 28676);
      float4 d0 = *(const float4*)(s + 28928);
      float4 d1 = *(const float4*)(s + 28932);
      ushort4v lo = { f2bf((a0.x + b0.x + c0.x + d0.x) * 0.25f),
                      f2bf((a0.y + b0.y + c0.y + d0.y) * 0.25f),
                      f2bf((a0.z + b0.z + c0.z + d0.z) * 0.25f),
                      f2bf((a0.w + b0.w + c0.w + d0.w) * 0.25f) };
      ushort4v hi = { f2bf((a1.x + b1.x + c1.x + d1.x) * 0.25f),
                      f2bf((a1.y + b1.y + c1.y + d1.y) * 0.25f),
                      f2bf((a1.z + b1.z + c1.z + d1.z) * 0.25f),
                      f2bf((a1.w + b1.w + c1.w + d1.w) * 0.25f) };
      *(ushort4v*)&sA[arow[cc] * 64 + cch] = lo;
      *(ushort4v*)&sA[arow[cc] * 64 + cch + 4] = hi;
    }
    __syncthreads();
#pragma unroll
    for (int ks = 0; ks < 2; ++ks) {
      short8 af[4], bfr[4];
#pragma unroll
      for (int i = 0; i < 4; ++i)
        af[i] = *(const short8*)&sA[(i * 16 + lr) * 64 + ks * 32 + lk8];
#pragma unroll
      for (int j = 0; j < 4; ++j)
        bfr[j] = *(const short8*)&sB[(wv * 64 + j * 16 + lr) * 64 + ks * 32 + lk8];
#pragma unroll
      for (int i = 0; i < 4; ++i)
#pragma unroll
        for (int j = 0; j < 4; ++j)
          acc[i][j] = __builtin_amdgcn_mfma_f32_16x16x32_bf16(af[i], bfr[j], acc[i][j], 0, 0, 0);
    }
    __syncthreads();
  }

  // epilogue: +bias, LN(256) across the 4 waves, GELU, bf16 store
  float bsv[4], gnv[4], bnv[4];
#pragma unroll
  for (int j = 0; j < 4; ++j) {
    int col = wv * 64 + j * 16 + lr;
    bsv[j] = bsr[col]; gnv[j] = gn[col]; bnv[j] = bn[col];
  }
  float s_[4][4], q_[4][4];
#pragma unroll
  for (int i = 0; i < 4; ++i)
#pragma unroll
    for (int r = 0; r < 4; ++r) {
      float s = 0.f, q = 0.f;
#pragma unroll
      for (int j = 0; j < 4; ++j) {
        float v = acc[i][j][r] + bsv[j];
        acc[i][j][r] = v;
        s += v; q += v * v;
      }
      s_[i][r] = s; q_[i][r] = q;
    }
#pragma unroll
  for (int m = 1; m <= 8; m <<= 1)
#pragma unroll
    for (int i = 0; i < 4; ++i)
#pragma unroll
      for (int r = 0; r < 4; ++r) {
        s_[i][r] += __shfl_xor(s_[i][r], m);
        q_[i][r] += __shfl_xor(q_[i][r], m);
      }
  if (lr == 0) {
#pragma unroll
    for (int i = 0; i < 4; ++i)
#pragma unroll
      for (int r = 0; r < 4; ++r) {
        int row = i * 16 + lr4 + r;
        red[row * 8 + wv * 2 + 0] = s_[i][r];
        red[row * 8 + wv * 2 + 1] = q_[i][r];
      }
  }
  __syncthreads();
#pragma unroll
  for (int i = 0; i < 4; ++i) {
#pragma unroll
    for (int r = 0; r < 4; ++r) {
      int row = i * 16 + lr4 + r;
      float sum = red[row * 8 + 0] + red[row * 8 + 2] + red[row * 8 + 4] + red[row * 8 + 6];
      float sq  = red[row * 8 + 1] + red[row * 8 + 3] + red[row * 8 + 5] + red[row * 8 + 7];
      float mean = sum * (1.f / 256.f);
      float var = sq * (1.f / 256.f) - mean * mean;
      float rstd = rsqrtf(var + 1e-5f);
#pragma unroll
      for (int j = 0; j < 4; ++j) {
        float t = (acc[i][j][r] - mean) * rstd * gnv[j] + bnv[j];
        t = 0.5f * t * (1.f + erff(t * 0.70710678118654752f));
        out[(size_t)(m0 + row) * 256 + wv * 64 + j * 16 + lr] = f2bf(t);
      }
    }
  }
}

// ---------- 128x128 bf16 MFMA GEMM: out[m,n] = sum_k A[m,k]*Bw[n,k] ----------
// EPI 0: q windows (bf16)   EPI 2: kv windows (bf16, outp=k_win, out2=v_win)
// EPI 3: f32 + bias (final out)
template<int K, int N, int EPI>
__global__ __launch_bounds__(256, 2)
void gemm128(const unsigned short* __restrict__ A,
             const unsigned short* __restrict__ Bw,
             void* __restrict__ outp,
             const float* __restrict__ bias,
             unsigned short* __restrict__ out2) {
  __shared__ unsigned short sA[128 * 64];
  __shared__ unsigned short sB[128 * 64];
  const int tid = threadIdx.x;
  const int wv = tid >> 6;
  const int lane = tid & 63;
  const int m0 = blockIdx.y * 128;
  const int n0 = blockIdx.x * 128;
  const int wm = (wv >> 1) * 64;
  const int wn = (wv & 1) * 64;
  const int lr = lane & 15;
  const int lk8 = (lane >> 4) * 8;
  const int lr4 = (lane >> 4) * 4;

  f32x4 acc[4][4];
#pragma unroll
  for (int i = 0; i < 4; ++i)
#pragma unroll
    for (int j = 0; j < 4; ++j) acc[i][j] = (f32x4){0.f, 0.f, 0.f, 0.f};

  const int srow = wv * 32 + (lane >> 3);
  const int scol = (lane & 7) * 8;
  const unsigned short* gA = A + (size_t)(m0 + srow) * K + scol;
  const unsigned short* gB = Bw + (size_t)(n0 + srow) * K + scol;

  for (int kt = 0; kt < K; kt += 64) {
#pragma unroll
    for (int c = 0; c < 4; ++c) {
      __builtin_amdgcn_global_load_lds(
          (const __attribute__((address_space(1))) void*)(gA + (size_t)(c * 8) * K + kt),
          (__attribute__((address_space(3))) void*)&sA[(wv * 32 + c * 8) * 64], 16, 0, 0);
      __builtin_amdgcn_global_load_lds(
          (const __attribute__((address_space(1))) void*)(gB + (size_t)(c * 8) * K + kt),
          (__attribute__((address_space(3))) void*)&sB[(wv * 32 + c * 8) * 64], 16, 0, 0);
    }
    __syncthreads();
#pragma unroll
    for (int ks = 0; ks < 2; ++ks) {
      short8 af[4], bfr[4];
#pragma unroll
      for (int i = 0; i < 4; ++i)
        af[i] = *(const short8*)&sA[(wm + i * 16 + lr) * 64 + ks * 32 + lk8];
#pragma unroll
      for (int j = 0; j < 4; ++j)
        bfr[j] = *(const short8*)&sB[(wn + j * 16 + lr) * 64 + ks * 32 + lk8];
#pragma unroll
      for (int i = 0; i < 4; ++i)
#pragma unroll
        for (int j = 0; j < 4; ++j)
          acc[i][j] = __builtin_amdgcn_mfma_f32_16x16x32_bf16(af[i], bfr[j], acc[i][j], 0, 0, 0);
    }
    __syncthreads();
  }

#pragma unroll
  for (int i = 0; i < 4; ++i) {
#pragma unroll
    for (int j = 0; j < 4; ++j) {
#pragma unroll
      for (int r = 0; r < 4; ++r) {
        const int gm = m0 + wm + i * 16 + lr4 + r;
        const int gc = n0 + wn + j * 16 + lr;
        const float v = acc[i][j][r];
        if constexpr (EPI == 3) {
          ((float*)outp)[(size_t)gm * N + gc] = v + bias[gc];
        } else if constexpr (EPI == 0) {
          const int b = gm / 3136, pos = gm % 3136;
          const int h = pos / 56, ww = pos % 56;
          const int head = gc >> 6, d = gc & 63;
          const size_t idx = ((((size_t)(b * 8 + head)) * 64 + (h / 7) * 8 + (ww / 7)) * 49
                              + (h % 7) * 7 + (ww % 7)) * 64 + d;
          ((unsigned short*)outp)[idx] = f2bf(v);
        } else { // EPI == 2: kv scatter
          const int b = gm / 3136, pos = gm % 3136;
          const int h = pos / 56, ww = pos % 56;
          const int sel = gc >> 9, cc = gc & 511;
          const int head = cc >> 6, d = cc & 63;
          unsigned short* dst = sel ? out2 : (unsigned short*)outp;
          const size_t idx = ((((size_t)(b * 8 + head)) * 64 + (h / 7) * 8 + (ww / 7)) * 49
                              + (h % 7) * 7 + (ww % 7)) * 64 + d;
          dst[idx] = f2bf(v);
        }
      }
    }
  }
}

// ---------- windowed attention: one block per (b, head, window) ----------
__global__ __launch_bounds__(256)
void attn_win(const unsigned short* __restrict__ qw,
              const unsigned short* __restrict__ kw,
              const unsigned short* __restrict__ vw,
              unsigned short* __restrict__ aout) {
  __shared__ unsigned short q_s[64 * 64];
  __shared__ unsigned short k_s[64 * 64];
  __shared__ unsigned short vT_s[64 * 72];
  __shared__ unsigned short p_s[64 * 72];

  const int tid = threadIdx.x;
  const int bx = blockIdx.x;
  const int wv = tid >> 6;
  const int lane = tid & 63;
  const int lr = lane & 15;
  const int lk8 = (lane >> 4) * 8;
  const int lr4 = (lane >> 4) * 4;

  const size_t base = (size_t)bx * 3136;
  for (int i = tid * 8; i < 4096; i += 2048) {
    uint4 zv = make_uint4(0u, 0u, 0u, 0u);
    uint4 qv = zv, kvv = zv;
    if (i < 3136) {
      qv  = *(const uint4*)&qw[base + i];
      kvv = *(const uint4*)&kw[base + i];
    }
    *(uint4*)&q_s[i] = qv;
    *(uint4*)&k_s[i] = kvv;
  }
  for (int i = tid * 8; i < 4096; i += 2048) {
    int j = i >> 6, d0 = i & 63;
    union { uint4 v; unsigned short u[8]; } t;
    t.v = make_uint4(0u, 0u, 0u, 0u);
    if (i < 3136) t.v = *(const uint4*)&vw[base + i];
#pragma unroll
    for (int e = 0; e < 8; ++e) vT_s[(d0 + e) * 72 + j] = t.u[e];
  }
  __syncthreads();

  f32x4 s[4];
#pragma unroll
  for (int j = 0; j < 4; ++j) s[j] = (f32x4){0.f, 0.f, 0.f, 0.f};
#pragma unroll
  for (int ks = 0; ks < 2; ++ks) {
    short8 aq = *(const short8*)&q_s[(wv * 16 + lr) * 64 + ks * 32 + lk8];
#pragma unroll
    for (int j = 0; j < 4; ++j) {
      short8 bk = *(const short8*)&k_s[(j * 16 + lr) * 64 + ks * 32 + lk8];
      s[j] = __builtin_amdgcn_mfma_f32_16x16x32_bf16(aq, bk, s[j], 0, 0, 0);
    }
  }
#pragma unroll
  for (int j = 0; j < 4; ++j) {
    if (j * 16 + lr >= 49) {
#pragma unroll
      for (int r = 0; r < 4; ++r) s[j][r] = -1e30f;
    }
  }
  float mx[4], sm[4];
#pragma unroll
  for (int r = 0; r < 4; ++r)
    mx[r] = fmaxf(fmaxf(s[0][r], s[1][r]), fmaxf(s[2][r], s[3][r]));
#pragma unroll
  for (int m = 1; m <= 8; m <<= 1)
#pragma unroll
    for (int r = 0; r < 4; ++r) mx[r] = fmaxf(mx[r], __shfl_xor(mx[r], m));
  const float cexp = 0.125f * 1.4426950408889634f;
  float pv[4][4];
#pragma unroll
  for (int j = 0; j < 4; ++j)
#pragma unroll
    for (int r = 0; r < 4; ++r)
      pv[j][r] = exp2f((s[j][r] - mx[r]) * cexp);
#pragma unroll
  for (int r = 0; r < 4; ++r)
    sm[r] = pv[0][r] + pv[1][r] + pv[2][r] + pv[3][r];
#pragma unroll
  for (int m = 1; m <= 8; m <<= 1)
#pragma unroll
    for (int r = 0; r < 4; ++r) sm[r] += __shfl_xor(sm[r], m);
#pragma unroll
  for (int r = 0; r < 4; ++r) sm[r] = 1.f / sm[r];
#pragma unroll
  for (int j = 0; j < 4; ++j)
#pragma unroll
    for (int r = 0; r < 4; ++r)
      p_s[(wv * 16 + lr4 + r) * 72 + j * 16 + lr] = f2bf(pv[j][r] * sm[r]);
  __syncthreads();

  f32x4 o[4];
#pragma unroll
  for (int dt = 0; dt < 4; ++dt) o[dt] = (f32x4){0.f, 0.f, 0.f, 0.f};
#pragma unroll
  for (int ks = 0; ks < 2; ++ks) {
    short8 pa = *(const short8*)&p_s[(wv * 16 + lr) * 72 + ks * 32 + lk8];
#pragma unroll
    for (int dt = 0; dt < 4; ++dt) {
      short8 vb = *(const short8*)&vT_s[(dt * 16 + lr) * 72 + ks * 32 + lk8];
      o[dt] = __builtin_amdgcn_mfma_f32_16x16x32_bf16(pa, vb, o[dt], 0, 0, 0);
    }
  }
  const int b = bx >> 9;
  const int head = (bx >> 6) & 7;
  const int win = bx & 63;
  const int ht = win >> 3, wt = win & 7;
#pragma unroll
  for (int r = 0; r < 4; ++r) {
    int prow = wv * 16 + lr4 + r;
    if (prow < 49) {
      int wr = prow / 7, wc = prow % 7;
      size_t gm = (size_t)b * 3136 + (ht * 7 + wr) * 56 + wt * 7 + wc;
#pragma unroll
      for (int dt = 0; dt < 4; ++dt)
        aout[gm * 512 + head * 64 + dt * 16 + lr] = f2bf(o[dt][r]);
    }
  }
}

// ---------- launcher ----------
extern "C" void kernel_launch(void* const* d_in, const int* in_sizes, int n_in,
                              void* d_out, int out_size, void* d_ws, size_t ws_size,
                              hipStream_t stream) {
  const float* x     = (const float*)d_in[0];
  const float* y     = (const float*)d_in[1];
  const float* Wq    = (const float*)d_in[2];
  const float* Wkv   = (const float*)d_in[3];
  const float* Wproj = (const float*)d_in[4];
  const float* bproj = (const float*)d_in[5];
  const float* Wsr   = (const float*)d_in[6];
  const float* bsr   = (const float*)d_in[7];
  const float* gn    = (const float*)d_in[8];
  const float* bn    = (const float*)d_in[9];
  float* out = (float*)d_out;

  // Workspace (bytes)
  char* ws = (char*)d_ws;
  unsigned short* Wq_b    = (unsigned short*)ws; ws += 524288;
  unsigned short* Wkv_b   = (unsigned short*)ws; ws += 524288;
  unsigned short* Wproj_b = (unsigned short*)ws; ws += 524288;
  unsigned short* Wsr_b   = (unsigned short*)ws; ws += 131072;
  unsigned short* regA    = (unsigned short*)ws; ws += 25690112; // xb -> attn_out
  unsigned short* q_win   = (unsigned short*)ws; ws += 25690112;
  unsigned short* regC    = (unsigned short*)ws; ws += 12845056; // y2 bf16 (25088x256)
  unsigned short* k_win   = (unsigned short*)ws; ws += 25690112;
  unsigned short* v_win   = (unsigned short*)ws; ws += 25690112;

  // all converts in one launch (x -> regA)
  cvt_all<<<13376, 256, 0, stream>>>(x, Wq, Wkv, Wproj, Wsr,
                                     regA, Wq_b, Wkv_b, Wproj_b, Wsr_b);

  // q projection -> window layout
  gemm128<512, 512, 0><<<dim3(4, 196), 256, 0, stream>>>(regA, Wq_b, q_win, nullptr, nullptr);

  // fused KV preprocess: pool -> conv -> bias -> LN -> GELU -> bf16
  sr_ln_gelu<<<392, 256, 0, stream>>>(y, Wsr_b, bsr, gn, bn, regC);

  // kv projection -> window layouts
  gemm128<256, 1024, 2><<<dim3(8, 196), 256, 0, stream>>>(regC, Wkv_b, k_win, nullptr, v_win);

  // windowed attention -> natural layout bf16 (reuses regA)
  attn_win<<<4096, 256, 0, stream>>>(q_win, k_win, v_win, regA);

  // output projection + bias -> f32 d_out
  gemm128<512, 512, 3><<<dim3(4, 196), 256, 0, stream>>>(regA, Wproj_b, out, bproj, nullptr);
}